// Round 8
// baseline (310.710 us; speedup 1.0000x reference)
//
#include <hip/hip_runtime.h>
#include <math.h>

#define Bn   128          // B'
#define Ech  512          // E
#define Dd   128          // D
#define NCNT 16384        // Bn * Dd  (BatchNorm reduction count)

typedef __bf16 bf16;
typedef __attribute__((ext_vector_type(8))) __bf16 bf16x8;
typedef __attribute__((ext_vector_type(4))) __bf16 bf16x4;
typedef __attribute__((ext_vector_type(4))) float f32x4;

__device__ __forceinline__ float gelu_exact(float x) {
    return 0.5f * x * (1.0f + erff(x * 0.70710678118654752f));
}

static __device__ __forceinline__ f32x4 mfma16(bf16x8 a, bf16x8 b, f32x4 c) {
    return __builtin_amdgcn_mfma_f32_16x16x32_bf16(a, b, c, 0, 0, 0);
}

// XOR swizzle on byte offsets (same on write and read — rule #21).
#define SWZ(byte, row) ((unsigned)(byte) ^ (((unsigned)(row) & 7u) << 4))

// ---------------------------------------------------------------------------
// k1: grouped conv1d (k=3, pad=1, groups=128) + bias + residual + GELU,
//     store q_pre (bf16, pre-BN), accumulate per-channel sum/sumsq (fp32).
// ---------------------------------------------------------------------------
__global__ __launch_bounds__(256) void k_conv_gelu_stats(
    const float* __restrict__ x, const float* __restrict__ cw,
    const float* __restrict__ cb, bf16* __restrict__ qpre,
    float* __restrict__ csum, float* __restrict__ csumsq)
{
    __shared__ float xt[64 * 128];
    const int n  = blockIdx.y;
    const int c0 = blockIdx.x * 64;
    const float* xb = x + (size_t)n * Ech * Dd + (size_t)c0 * Dd;

    const float4* xb4 = (const float4*)xb;
    float4* xt4 = (float4*)xt;
    #pragma unroll
    for (int j = 0; j < 8; j++) xt4[threadIdx.x + 256 * j] = xb4[threadIdx.x + 256 * j];
    __syncthreads();

    const int oloc = threadIdx.x >> 2;
    const int hq   = threadIdx.x & 3;
    const int o    = c0 + oloc;
    const int gb   = oloc & ~3;

    float w[4][3];
    #pragma unroll
    for (int i = 0; i < 4; i++)
        #pragma unroll
        for (int kk = 0; kk < 3; kk++) w[i][kk] = cw[o * 12 + i * 3 + kk];
    const float bias = cb[o];

    float s = 0.f, ss = 0.f;
    bf16* qrow = qpre + (size_t)n * Ech * Dd + (size_t)o * Dd;
    #pragma unroll 4
    for (int j = 0; j < 32; j++) {
        const int h = hq + 4 * j;
        float acc = bias;
        #pragma unroll
        for (int i = 0; i < 4; i++) {
            const float* row = &xt[(gb + i) * 128];
            const float xm = (h > 0)   ? row[h - 1] : 0.f;
            const float xc = row[h];
            const float xp = (h < 127) ? row[h + 1] : 0.f;
            acc = fmaf(xm, w[i][0], acc);
            acc = fmaf(xc, w[i][1], acc);
            acc = fmaf(xp, w[i][2], acc);
        }
        acc += xt[oloc * 128 + h];
        const float g = gelu_exact(acc);
        qrow[h] = (bf16)g;
        s += g; ss = fmaf(g, g, ss);
    }
    s  += __shfl_xor(s, 1);  s  += __shfl_xor(s, 2);
    ss += __shfl_xor(ss, 1); ss += __shfl_xor(ss, 2);
    if (hq == 0) { atomicAdd(&csum[o], s); atomicAdd(&csumsq[o], ss); }
}

// ---------------------------------------------------------------------------
// k2: finalize BN stats -> per-channel scale/shift
// ---------------------------------------------------------------------------
__global__ void k_stats_final(const float* __restrict__ csum,
                              const float* __restrict__ csumsq,
                              const float* __restrict__ gamma,
                              const float* __restrict__ beta,
                              float* __restrict__ scale, float* __restrict__ shift)
{
    const int c = threadIdx.x;
    if (c < Ech) {
        const float mu   = csum[c]   * (1.0f / NCNT);
        const float var  = csumsq[c] * (1.0f / NCNT) - mu * mu;
        const float rstd = rsqrtf(var + 1e-5f);
        const float sc   = gamma[c] * rstd;
        scale[c] = sc;
        shift[c] = beta[c] - mu * sc;
    }
}

// ---------------------------------------------------------------------------
// k3: k = gelu(softmax(x, axis=E)) -> bf16. Register-cached single-pass.
// grid (4,128), block 256.
// ---------------------------------------------------------------------------
__global__ __launch_bounds__(256) void k_softmax_e_gelu_v2(
    const float* __restrict__ x, bf16* __restrict__ kout)
{
    __shared__ float4 red[32][8];
    const int n  = blockIdx.y;
    const int qd = blockIdx.x;
    const int t  = threadIdx.x;
    const int d4 = t & 7;
    const int eg = t >> 3;
    const float* xb = x + (size_t)n * Ech * Dd + qd * 32 + d4 * 4;

    float4 vb[16];
    float4 m4 = {-3e38f, -3e38f, -3e38f, -3e38f};
    #pragma unroll
    for (int j = 0; j < 16; j++) {
        const int e = eg + 32 * j;
        float4 v = *(const float4*)(xb + (size_t)e * Dd);
        vb[j] = v;
        m4.x = fmaxf(m4.x, v.x); m4.y = fmaxf(m4.y, v.y);
        m4.z = fmaxf(m4.z, v.z); m4.w = fmaxf(m4.w, v.w);
    }
    red[eg][d4] = m4;
    __syncthreads();
    #pragma unroll
    for (int s = 16; s >= 1; s >>= 1) {
        if (eg < s) {
            float4 a = red[eg][d4], b = red[eg + s][d4];
            a.x = fmaxf(a.x, b.x); a.y = fmaxf(a.y, b.y);
            a.z = fmaxf(a.z, b.z); a.w = fmaxf(a.w, b.w);
            red[eg][d4] = a;
        }
        __syncthreads();
    }
    m4 = red[0][d4];
    __syncthreads();

    float4 s4 = {0.f, 0.f, 0.f, 0.f};
    #pragma unroll
    for (int j = 0; j < 16; j++) {
        float4 v = vb[j];
        v.x = __expf(v.x - m4.x); v.y = __expf(v.y - m4.y);
        v.z = __expf(v.z - m4.z); v.w = __expf(v.w - m4.w);
        vb[j] = v;
        s4.x += v.x; s4.y += v.y; s4.z += v.z; s4.w += v.w;
    }
    red[eg][d4] = s4;
    __syncthreads();
    #pragma unroll
    for (int s = 16; s >= 1; s >>= 1) {
        if (eg < s) {
            float4 a = red[eg][d4], b = red[eg + s][d4];
            a.x += b.x; a.y += b.y; a.z += b.z; a.w += b.w;
            red[eg][d4] = a;
        }
        __syncthreads();
    }
    s4 = red[0][d4];
    const float4 inv4 = {1.0f / s4.x, 1.0f / s4.y, 1.0f / s4.z, 1.0f / s4.w};

    bf16* kb = kout + (size_t)n * Ech * Dd + qd * 32 + d4 * 4;
    #pragma unroll
    for (int j = 0; j < 16; j++) {
        const int e = eg + 32 * j;
        float4 p = vb[j];
        bf16x4 ov;
        ov[0] = (bf16)gelu_exact(p.x * inv4.x);
        ov[1] = (bf16)gelu_exact(p.y * inv4.y);
        ov[2] = (bf16)gelu_exact(p.z * inv4.z);
        ov[3] = (bf16)gelu_exact(p.w * inv4.w);
        *(bf16x4*)(kb + (size_t)e * Dd) = ov;
    }
}

// ---------------------------------------------------------------------------
// k_vgemm_T: vT[n,o,e] = gelu( sum_d lw[o,d]*x[n,e,d] + lb[o] )   (bf16 out)
// grid (8 e, 2 o, 128 n), block 256. 64x64 tile, [64][128] swizzled LDS.
// ---------------------------------------------------------------------------
__global__ __launch_bounds__(256) void k_vgemm_T(
    const float* __restrict__ x, const float* __restrict__ lw,
    const float* __restrict__ lb, bf16* __restrict__ vT)
{
    __shared__ bf16 As[64 * 128];
    __shared__ bf16 Bs[64 * 128];
    const int n = blockIdx.z, e0 = blockIdx.x * 64, o0 = blockIdx.y * 64;
    const int t = threadIdx.x, lane = t & 63, w = t >> 6;
    const int wr = w >> 1, wc = w & 1;
    const int lr = lane & 15, lg = lane >> 4;

    // stage (f32 -> bf16, swizzled)
    {
        const float* sa = lw + (size_t)o0 * Dd;
        const float* sb = x + (size_t)n * Ech * Dd + (size_t)e0 * Dd;
        #pragma unroll
        for (int p = 0; p < 4; p++) {
            const int idx = t + 256 * p;
            const int row = idx >> 4, k16 = idx & 15;
            float4 a0 = *(const float4*)(sa + (size_t)row * Dd + k16 * 8);
            float4 a1 = *(const float4*)(sa + (size_t)row * Dd + k16 * 8 + 4);
            bf16x8 oa;
            oa[0]=(bf16)a0.x; oa[1]=(bf16)a0.y; oa[2]=(bf16)a0.z; oa[3]=(bf16)a0.w;
            oa[4]=(bf16)a1.x; oa[5]=(bf16)a1.y; oa[6]=(bf16)a1.z; oa[7]=(bf16)a1.w;
            *(bf16x8*)((char*)As + SWZ(row * 256 + k16 * 16, row)) = oa;
            float4 b0 = *(const float4*)(sb + (size_t)row * Dd + k16 * 8);
            float4 b1 = *(const float4*)(sb + (size_t)row * Dd + k16 * 8 + 4);
            bf16x8 ob;
            ob[0]=(bf16)b0.x; ob[1]=(bf16)b0.y; ob[2]=(bf16)b0.z; ob[3]=(bf16)b0.w;
            ob[4]=(bf16)b1.x; ob[5]=(bf16)b1.y; ob[6]=(bf16)b1.z; ob[7]=(bf16)b1.w;
            *(bf16x8*)((char*)Bs + SWZ(row * 256 + k16 * 16, row)) = ob;
        }
    }
    __syncthreads();

    f32x4 acc[2][2] = {};
    #pragma unroll
    for (int ks = 0; ks < 4; ks++) {
        const int ko = ks * 32 + lg * 8;
        const int ra0 = wr * 32 + lr, ra1 = wr * 32 + 16 + lr;
        const int rb0 = wc * 32 + lr, rb1 = wc * 32 + 16 + lr;
        const bf16x8 a0 = *(const bf16x8*)((char*)As + SWZ(ra0 * 256 + ko * 2, ra0));
        const bf16x8 a1 = *(const bf16x8*)((char*)As + SWZ(ra1 * 256 + ko * 2, ra1));
        const bf16x8 b0 = *(const bf16x8*)((char*)Bs + SWZ(rb0 * 256 + ko * 2, rb0));
        const bf16x8 b1 = *(const bf16x8*)((char*)Bs + SWZ(rb1 * 256 + ko * 2, rb1));
        acc[0][0] = mfma16(a0, b0, acc[0][0]);
        acc[0][1] = mfma16(a0, b1, acc[0][1]);
        acc[1][0] = mfma16(a1, b0, acc[1][0]);
        acc[1][1] = mfma16(a1, b1, acc[1][1]);
    }

    bf16* vb = vT + (size_t)n * Dd * Ech;
    #pragma unroll
    for (int mm = 0; mm < 2; mm++) {
        #pragma unroll
        for (int nn = 0; nn < 2; nn++) {
            const int ecol = e0 + wc * 32 + nn * 16 + lr;
            #pragma unroll
            for (int r4 = 0; r4 < 4; r4++) {
                const int orow = o0 + wr * 32 + mm * 16 + lg * 4 + r4;
                vb[(size_t)orow * Ech + ecol] =
                    (bf16)gelu_exact(acc[mm][nn][r4] + lb[orow]);
            }
        }
    }
}

// ---------------------------------------------------------------------------
// k_attn_fused2: flash-style attention, 80 KB LDS -> 2 blocks/CU.
//   Q in registers (BN folded). K in 2x64KB chunks. P (64x512 bf16, 64 KB)
//   reuses the K buffer. V in 8x16KB chunks. Each B-fragment read feeds
//   2 MFMAs (2 row-tiles/wave).
// LDS map: [0,64K) K-chunk then P | [64K,80K) smred then V-chunk
// grid (8 e-strips, 128 n), block 256 (4 waves: wr=row-half, wc=col-half).
// ---------------------------------------------------------------------------
#define KP_OFF  0
#define SMR_OFF 65536
#define VC_OFF  65536
#define ATT_LDS 81920

__global__ __launch_bounds__(256) void k_attn_fused2(
    const bf16* __restrict__ qpre, const bf16* __restrict__ kbuf,
    const bf16* __restrict__ vT, const float* __restrict__ scale,
    const float* __restrict__ shift, float* __restrict__ attn,
    float* __restrict__ out)
{
    __shared__ char lds[ATT_LDS];
    const int n = blockIdx.y, e0 = blockIdx.x * 64;
    const int t = threadIdx.x, lane = t & 63, w = t >> 6;
    const int wr = w >> 1, wc = w & 1;
    const int lr = lane & 15, lg = lane >> 4;

    // ---- Q into registers, BN applied: rows wr*32 + rt*16 + lr ----
    bf16x8 qa[2][4];
    #pragma unroll
    for (int rt = 0; rt < 2; rt++) {
        const int row = e0 + wr * 32 + rt * 16 + lr;
        const float sc = scale[row], sh = shift[row];
        const bf16* qr = qpre + (size_t)n * Ech * Dd + (size_t)row * Dd + lg * 8;
        #pragma unroll
        for (int ks = 0; ks < 4; ks++) {
            bf16x8 v = *(const bf16x8*)(qr + ks * 32);
            bf16x8 o;
            #pragma unroll
            for (int j = 0; j < 8; j++) o[j] = (bf16)fmaf((float)v[j], sc, sh);
            qa[rt][ks] = o;
        }
    }

    // ---- QK over 2 K-chunks of 256 f-rows ----
    f32x4 acc[2][16];
    #pragma unroll
    for (int rt = 0; rt < 2; rt++)
        #pragma unroll
        for (int j = 0; j < 16; j++) acc[rt][j] = (f32x4){0.f, 0.f, 0.f, 0.f};

    const bf16* kb = kbuf + (size_t)n * Ech * Dd;
    #pragma unroll
    for (int c = 0; c < 2; c++) {
        __syncthreads();                    // prev chunk's reads done
        #pragma unroll
        for (int p = 0; p < 16; p++) {      // stage 256x128 bf16 = 4096 float4
            const int idx = t + 256 * p;
            const int row = idx >> 4, k16 = idx & 15;
            float4 v = *(const float4*)(kb + (size_t)(c * 256 + row) * Dd + k16 * 8);
            *(float4*)(lds + KP_OFF + SWZ(row * 256 + k16 * 16, row)) = v;
        }
        __syncthreads();
        #pragma unroll
        for (int ks = 0; ks < 4; ks++)
            #pragma unroll
            for (int ct = 0; ct < 8; ct++) {
                const int brow = wc * 128 + ct * 16 + lr;
                const bf16x8 b = *(const bf16x8*)(lds + KP_OFF +
                                   SWZ(brow * 256 + ks * 64 + lg * 16, brow));
                acc[0][c * 8 + ct] = mfma16(qa[0][ks], b, acc[0][c * 8 + ct]);
                acc[1][c * 8 + ct] = mfma16(qa[1][ks], b, acc[1][c * 8 + ct]);
            }
    }

    // ---- softmax: in-register + 1-round cross-wave (wc) combine ----
    // lane's acc[rt][j][r4] = S[row = wr*32+rt*16+lg*4+r4][f = (j>>3)*256 + wc*128 + (j&7)*16 + lr]
    const float rsc = 0.044194173824159216f;   // 1/sqrt(512)
    float mloc[2][4], sloc[2][4];
    #pragma unroll
    for (int rt = 0; rt < 2; rt++)
        #pragma unroll
        for (int r4 = 0; r4 < 4; r4++) mloc[rt][r4] = -3e38f;
    #pragma unroll
    for (int rt = 0; rt < 2; rt++)
        #pragma unroll
        for (int j = 0; j < 16; j++)
            #pragma unroll
            for (int r4 = 0; r4 < 4; r4++)
                mloc[rt][r4] = fmaxf(mloc[rt][r4], acc[rt][j][r4]);
    #pragma unroll
    for (int off = 1; off <= 8; off <<= 1)
        #pragma unroll
        for (int rt = 0; rt < 2; rt++)
            #pragma unroll
            for (int r4 = 0; r4 < 4; r4++)
                mloc[rt][r4] = fmaxf(mloc[rt][r4], __shfl_xor(mloc[rt][r4], off));

    #pragma unroll
    for (int rt = 0; rt < 2; rt++)
        #pragma unroll
        for (int r4 = 0; r4 < 4; r4++) sloc[rt][r4] = 0.f;
    #pragma unroll
    for (int rt = 0; rt < 2; rt++)
        #pragma unroll
        for (int j = 0; j < 16; j++)
            #pragma unroll
            for (int r4 = 0; r4 < 4; r4++) {
                const float p = __expf((acc[rt][j][r4] - mloc[rt][r4]) * rsc);
                acc[rt][j][r4] = p;
                sloc[rt][r4] += p;
            }
    #pragma unroll
    for (int off = 1; off <= 8; off <<= 1)
        #pragma unroll
        for (int rt = 0; rt < 2; rt++)
            #pragma unroll
            for (int r4 = 0; r4 < 4; r4++)
                sloc[rt][r4] += __shfl_xor(sloc[rt][r4], off);

    float* pmax = (float*)(lds + SMR_OFF);         // [2][64]
    float* psum = (float*)(lds + SMR_OFF + 512);   // [2][64]
    if (lr == 0) {
        #pragma unroll
        for (int rt = 0; rt < 2; rt++)
            #pragma unroll
            for (int r4 = 0; r4 < 4; r4++) {
                const int row = wr * 32 + rt * 16 + lg * 4 + r4;
                pmax[wc * 64 + row] = mloc[rt][r4];
                psum[wc * 64 + row] = sloc[rt][r4];
            }
    }
    __syncthreads();   // all QK reads + smred writes done; K region now dead

    float fac[2][4];
    #pragma unroll
    for (int rt = 0; rt < 2; rt++)
        #pragma unroll
        for (int r4 = 0; r4 < 4; r4++) {
            const int row = wr * 32 + rt * 16 + lg * 4 + r4;
            const float m0 = pmax[row], m1 = pmax[64 + row];
            const float s0 = psum[row], s1 = psum[64 + row];
            const float M  = fmaxf(m0, m1);
            const float S  = s0 * __expf((m0 - M) * rsc) + s1 * __expf((m1 - M) * rsc);
            fac[rt][r4] = __expf((mloc[rt][r4] - M) * rsc) / S;
        }

    // ---- write P (bf16) into [0,64K), rows 1024 B, swizzled ----
    #pragma unroll
    for (int rt = 0; rt < 2; rt++)
        #pragma unroll
        for (int j = 0; j < 16; j++)
            #pragma unroll
            for (int r4 = 0; r4 < 4; r4++) {
                const int row = wr * 32 + rt * 16 + lg * 4 + r4;
                const int col = (j >> 3) * 256 + wc * 128 + (j & 7) * 16 + lr;
                *(bf16*)(lds + KP_OFF + SWZ(row * 1024 + col * 2, row)) =
                    (bf16)(acc[rt][j][r4] * fac[rt][r4]);
            }
    __syncthreads();   // P complete

    // ---- write attn (f32) from P, coalesced ----
    {
        float* ab = attn + (size_t)n * Ech * Ech + (size_t)e0 * Ech;
        #pragma unroll
        for (int p = 0; p < 32; p++) {
            const int idx = t + 256 * p;           // 8192 float4: 64 rows x 128
            const int row = idx >> 7, c4 = idx & 127;
            bf16x4 pv = *(const bf16x4*)(lds + KP_OFF + SWZ(row * 1024 + c4 * 8, row));
            float4 o = {(float)pv[0], (float)pv[1], (float)pv[2], (float)pv[3]};
            *(float4*)(ab + (size_t)row * Ech + c4 * 4) = o;
        }
    }

    // ---- PV over 8 V-chunks of 64 f; wave covers 32 e-rows x 64 d-cols ----
    const bf16* vsrc = vT + (size_t)n * Dd * Ech;
    f32x4 acc2[2][4];
    #pragma unroll
    for (int rt = 0; rt < 2; rt++)
        #pragma unroll
        for (int dtt = 0; dtt < 4; dtt++) acc2[rt][dtt] = (f32x4){0.f, 0.f, 0.f, 0.f};

    #pragma unroll
    for (int fc = 0; fc < 8; fc++) {
        __syncthreads();                    // prev V reads done (iter0: smred dead)
        #pragma unroll
        for (int p = 0; p < 4; p++) {       // stage 128 rows x 64 f bf16 = 1024 float4
            const int idx = t + 256 * p;
            const int row = idx >> 3, c16 = idx & 7;
            float4 v = *(const float4*)(vsrc + (size_t)row * Ech + fc * 64 + c16 * 8);
            *(float4*)(lds + VC_OFF + SWZ(row * 128 + c16 * 16, row)) = v;
        }
        __syncthreads();
        #pragma unroll
        for (int ks2 = 0; ks2 < 2; ks2++) {
            const int fcol = fc * 64 + ks2 * 32 + lg * 8;
            const int ar0 = wr * 32 + lr, ar1 = wr * 32 + 16 + lr;
            const bf16x8 a0 = *(const bf16x8*)(lds + KP_OFF + SWZ(ar0 * 1024 + fcol * 2, ar0));
            const bf16x8 a1 = *(const bf16x8*)(lds + KP_OFF + SWZ(ar1 * 1024 + fcol * 2, ar1));
            #pragma unroll
            for (int dtt = 0; dtt < 4; dtt++) {
                const int brow = wc * 64 + dtt * 16 + lr;
                const bf16x8 b = *(const bf16x8*)(lds + VC_OFF +
                                   SWZ(brow * 128 + ks2 * 64 + lg * 16, brow));
                acc2[0][dtt] = mfma16(a0, b, acc2[0][dtt]);
                acc2[1][dtt] = mfma16(a1, b, acc2[1][dtt]);
            }
        }
    }

    // ---- write out ----
    float* ob = out + (size_t)n * Ech * Dd;
    #pragma unroll
    for (int rt = 0; rt < 2; rt++)
        #pragma unroll
        for (int dtt = 0; dtt < 4; dtt++)
            #pragma unroll
            for (int r4 = 0; r4 < 4; r4++) {
                const int erow = e0 + wr * 32 + rt * 16 + lg * 4 + r4;
                const int dcol = wc * 64 + dtt * 16 + lr;
                ob[(size_t)erow * Dd + dcol] = acc2[rt][dtt][r4];
            }
}

// ---------------------------------------------------------------------------
extern "C" void kernel_launch(void* const* d_in, const int* in_sizes, int n_in,
                              void* d_out, int out_size, void* d_ws, size_t ws_size,
                              hipStream_t stream)
{
    const float* x     = (const float*)d_in[0];
    const float* cw    = (const float*)d_in[1];
    const float* cb    = (const float*)d_in[2];
    const float* gamma = (const float*)d_in[3];
    const float* beta  = (const float*)d_in[4];
    const float* lw    = (const float*)d_in[5];
    const float* lb    = (const float*)d_in[6];

    float* out  = (float*)d_out;                  // 8,388,608 floats
    float* attn = out + (size_t)8388608;          // 33,554,432 floats

    bf16*  qpre_bf = (bf16*)d_ws;                 // 16 MB
    bf16*  kb_bf   = qpre_bf + 8388608;           // 16 MB
    bf16*  vT_bf   = kb_bf + 8388608;             // 16 MB
    float* csum    = (float*)(vT_bf + 8388608);   // 512
    float* csumsq  = csum + 512;
    float* scale   = csumsq + 512;
    float* shift   = scale + 512;

    hipMemsetAsync(csum, 0, 2 * 512 * sizeof(float), stream);

    k_conv_gelu_stats<<<dim3(8, 128), 256, 0, stream>>>(x, cw, cb, qpre_bf, csum, csumsq);
    k_stats_final<<<1, 512, 0, stream>>>(csum, csumsq, gamma, beta, scale, shift);
    k_softmax_e_gelu_v2<<<dim3(4, 128), 256, 0, stream>>>(x, kb_bf);
    k_vgemm_T<<<dim3(8, 2, 128), 256, 0, stream>>>(x, lw, lb, vT_bf);
    k_attn_fused2<<<dim3(8, 128), 256, 0, stream>>>(
        qpre_bf, kb_bf, vT_bf, scale, shift, attn, out);
}